// Round 7
// baseline (156.606 us; speedup 1.0000x reference)
//
#include <hip/hip_runtime.h>
#include <cstddef>
#include <cstdint>

// DigitCaps dynamic routing, fully fused.
// Round 7 = round 6 with compile fix: __builtin_amdgcn_cvt_pkrtz returns an
// __fp16-based vector; bit-cast it to our _Float16-based h2 via cvt_pk().
// Design under test (unchanged from round 6):
//  - batch-pair state packed as f16x2 (v_pk_* math, cvt_pkrtz packing)
//  - 16-lane logit reduce via __shfl_xor (ds_bpermute, LDS pipe) instead of
//    DPP (VALU pipe), one packed reduce serves both batch items
//  - softmax without max-subtraction (logits bounded, exp safe in f32)
// Theory: round-5 was VALU-issue-bound (~34K wave-inst/wave vs ~16K useful),
// with AGPR round-trips for the oversized live set (VGPR_Count=60 < ~80 live).
//
// B=512, O=10, I=1152, OW=16, S=8, ITER=3.
//   pass0: c=0.1 uniform -> s1 = 0.1*sum_i u ; v1   (f32 accum, light)
//   pass1: b = u.v1       -> softmax -> s2 ; v2     (packed f16)
//   pass2: b = u.(v1+v2)  -> softmax -> s3 ; out    (packed f16)
// u recomputed per pass from f16 W (transposed [i][o][w][s] in d_ws, 2.95 MB,
// L2-resident) and f16 x (staged once in LDS).

typedef _Float16 h2 __attribute__((ext_vector_type(2)));
typedef __fp16 fp16v2 __attribute__((ext_vector_type(2)));  // cvt_pkrtz return type

constexpr int O_ = 10, I_ = 1152, W_ = 16, S_ = 8;
constexpr int BQ = 2;               // batch items per block
constexpr int NTH = 1024, NWV = 16;
constexpr int SLOTS = NWV * 4;      // 64 concurrent i (16 lanes per i)
constexpr int KSEQ = I_ / SLOTS;    // 18 sequential i per lane per pass
constexpr int WROW = O_ * W_ * S_;  // 1280 halves per i in transposed W

union U32H2 { uint32_t u; h2 h; fp16v2 f; };
__device__ __forceinline__ h2 as_h2(uint32_t u) { U32H2 c; c.u = u; return c.h; }
__device__ __forceinline__ uint32_t as_u32(h2 h) { U32H2 c; c.h = h; return c.u; }
__device__ __forceinline__ h2 cvt_pk(float a, float b) {
  U32H2 c; c.f = __builtin_amdgcn_cvt_pkrtz(a, b); return c.h;
}

// W prep: fp32 [o][i][w][s] -> f16 [i][o][w][s]  (2,949,120 B into d_ws)
constexpr int W4TOT = O_ * I_ * W_ * S_ / 4;  // 368640 float4s
__global__ __launch_bounds__(256) void wprep(const float4* __restrict__ Wg,
                                             uint2* __restrict__ Wt) {
  int idx = blockIdx.x * 256 + threadIdx.x;
  if (idx >= W4TOT) return;
  int w2 = idx & 31;        // which float4 within the (o,i) row of 128 floats
  int oi = idx >> 5;        // o*I_ + i
  int o = oi / I_;
  int i = oi - o * I_;
  float4 v = Wg[idx];
  uint2 pk;
  pk.x = as_u32(cvt_pk(v.x, v.y));
  pk.y = as_u32(cvt_pk(v.z, v.w));
  Wt[(i * O_ + o) * 32 + w2] = pk;
}

__device__ __forceinline__ float dot8(const uint4& wv, const uint32_t* xr) {
  return __builtin_amdgcn_fdot2(as_h2(wv.x), as_h2(xr[0]),
          __builtin_amdgcn_fdot2(as_h2(wv.y), as_h2(xr[1]),
           __builtin_amdgcn_fdot2(as_h2(wv.z), as_h2(xr[2]),
            __builtin_amdgcn_fdot2(as_h2(wv.w), as_h2(xr[3]),
                                   0.f, false), false), false), false);
}

__global__ __launch_bounds__(NTH, 1) void digitcaps_fused(
    const float* __restrict__ xg, const _Float16* __restrict__ Wt,
    float* __restrict__ out) {
  __shared__ _Float16 xl[BQ * I_ * S_];      // 36,864 B  (f16 x, whole block)
  __shared__ float s_buf[NWV][BQ][O_][W_];   // 20,480 B
  __shared__ float vcur[BQ][O_ * W_];        // v1, then v1+v2 (agreement vector)
  __shared__ float v1s[BQ][O_ * W_];

  const int tid = threadIdx.x, blk = blockIdx.x;
  const int wave = tid >> 6, lane = tid & 63;
  const int wg = lane & 15;     // w column 0..15 (one per lane)
  const int isub = lane >> 4;   // 0..3 : i within the wave

  // ---- stage x -> f16 LDS (once; reused by all 3 passes) ----
  {
    const float4* xb = (const float4*)(xg + (size_t)blk * (BQ * I_ * S_));
    uint2* xw = (uint2*)xl;
#pragma unroll
    for (int j = 0; j < 5; ++j) {
      int f = j * NTH + tid;            // float4 index, 4608 total
      if (f < BQ * I_ * S_ / 4) {
        float4 v = xb[f];
        uint2 pk;
        pk.x = as_u32(cvt_pk(v.x, v.y));
        pk.y = as_u32(cvt_pk(v.z, v.w));
        xw[f] = pk;
      }
    }
  }
  __syncthreads();

  const int ib = wave * 4 + isub;  // i-slot; i = ib + 64*k

  // ================= pass 0 : c = 1/10 uniform (f32 accumulate) ============
  {
    float S[BQ][O_];
#pragma unroll
    for (int b = 0; b < BQ; ++b)
#pragma unroll
      for (int o = 0; o < O_; ++o) S[b][o] = 0.f;

#pragma unroll 2
    for (int k = 0; k < KSEQ; ++k) {
      const int i = ib + SLOTS * k;
      uint32_t xr[BQ][4];
#pragma unroll
      for (int b = 0; b < BQ; ++b) {
        uint4 t = *(const uint4*)&xl[(b * I_ + i) * S_];
        xr[b][0] = t.x; xr[b][1] = t.y; xr[b][2] = t.z; xr[b][3] = t.w;
      }
      const _Float16* wi = Wt + (size_t)i * WROW + wg * S_;
#pragma unroll
      for (int o = 0; o < O_; ++o) {
        uint4 wv = *(const uint4*)(wi + o * (W_ * S_));
#pragma unroll
        for (int b = 0; b < BQ; ++b) S[b][o] += dot8(wv, xr[b]);
      }
    }
#pragma unroll
    for (int b = 0; b < BQ; ++b)
#pragma unroll
      for (int o = 0; o < O_; ++o) {
        float s = S[b][o];
        s += __shfl_xor(s, 16);
        s += __shfl_xor(s, 32);
        S[b][o] = s;
      }
    if (isub == 0) {
#pragma unroll
      for (int b = 0; b < BQ; ++b)
#pragma unroll
        for (int o = 0; o < O_; ++o) s_buf[wave][b][o][wg] = S[b][o];
    }
    __syncthreads();

    if (tid < BQ * O_ * W_) {
      const int bb = tid / (O_ * W_);
      const int r = tid % (O_ * W_);
      float s = 0.f;
#pragma unroll
      for (int wv = 0; wv < NWV; ++wv) s += s_buf[wv][bb][r >> 4][r & 15];
      s *= 0.1f;
      float n2 = s * s;
      n2 += __shfl_xor(n2, 1);
      n2 += __shfl_xor(n2, 2);
      n2 += __shfl_xor(n2, 4);
      n2 += __shfl_xor(n2, 8);
      const float v = s * sqrtf(n2) / (1.0f + n2);
      vcur[bb][r] = v;
      v1s[bb][r] = v;
    }
    __syncthreads();
  }

  // ============== passes 1,2 : packed-f16 routing ==========================
  for (int pass = 1; pass < 3; ++pass) {
    // per-lane packed v slice: (b0,b1) for this lane's w column
    h2 vrpk[O_];
#pragma unroll
    for (int o = 0; o < O_; ++o)
      vrpk[o] = cvt_pk(vcur[0][o * W_ + wg], vcur[1][o * W_ + wg]);
    h2 Spk[O_];
#pragma unroll
    for (int o = 0; o < O_; ++o) Spk[o] = h2{(_Float16)0, (_Float16)0};

#pragma unroll 2
    for (int k = 0; k < KSEQ; ++k) {
      const int i = ib + SLOTS * k;
      uint32_t xr[BQ][4];
#pragma unroll
      for (int b = 0; b < BQ; ++b) {
        uint4 t = *(const uint4*)&xl[(b * I_ + i) * S_];
        xr[b][0] = t.x; xr[b][1] = t.y; xr[b][2] = t.z; xr[b][3] = t.w;
      }
      const _Float16* wi = Wt + (size_t)i * WROW + wg * S_;
      h2 upk[O_], ppk[O_];
#pragma unroll
      for (int o = 0; o < O_; ++o) {
        uint4 wv = *(const uint4*)(wi + o * (W_ * S_));
        float u0 = dot8(wv, xr[0]);
        float u1 = dot8(wv, xr[1]);
        upk[o] = cvt_pk(u0, u1);
        ppk[o] = upk[o] * vrpk[o];          // v_pk_mul_f16
      }
      // logit: sum over the 16 w lanes (bits 0..3), packed (both b at once),
      // via ds_bpermute (LDS pipe) + v_pk_add_f16
#pragma unroll
      for (int o = 0; o < O_; ++o) {
#pragma unroll
        for (int d = 1; d <= 8; d <<= 1)
          ppk[o] = ppk[o] + as_h2((uint32_t)__shfl_xor((int)as_u32(ppk[o]), d));
      }
      // softmax over o (no max-sub: |logit| <~ 8, f32 exp safe)
      float e0[O_], e1[O_];
      float es0 = 0.f, es1 = 0.f;
#pragma unroll
      for (int o = 0; o < O_; ++o) {
        e0[o] = __expf((float)ppk[o][0]); es0 += e0[o];
        e1[o] = __expf((float)ppk[o][1]); es1 += e1[o];
      }
      const float inv0 = 1.0f / es0, inv1 = 1.0f / es1;
#pragma unroll
      for (int o = 0; o < O_; ++o) {
        h2 c = cvt_pk(e0[o] * inv0, e1[o] * inv1);
        Spk[o] = Spk[o] + c * upk[o];       // packed mul+add
      }
    }

    // reduce packed s over the 4 i-sub lane groups (bits 4,5)
#pragma unroll
    for (int o = 0; o < O_; ++o) {
      Spk[o] = Spk[o] + as_h2((uint32_t)__shfl_xor((int)as_u32(Spk[o]), 16));
      Spk[o] = Spk[o] + as_h2((uint32_t)__shfl_xor((int)as_u32(Spk[o]), 32));
    }
    if (isub == 0) {
#pragma unroll
      for (int o = 0; o < O_; ++o) {
        s_buf[wave][0][o][wg] = (float)Spk[o][0];
        s_buf[wave][1][o][wg] = (float)Spk[o][1];
      }
    }
    __syncthreads();

    // cross-wave reduce + squash on 320 threads
    if (tid < BQ * O_ * W_) {
      const int bb = tid / (O_ * W_);
      const int r = tid % (O_ * W_);
      float s = 0.f;
#pragma unroll
      for (int wv = 0; wv < NWV; ++wv) s += s_buf[wv][bb][r >> 4][r & 15];
      float n2 = s * s;
      n2 += __shfl_xor(n2, 1);
      n2 += __shfl_xor(n2, 2);
      n2 += __shfl_xor(n2, 4);
      n2 += __shfl_xor(n2, 8);
      const float v = s * sqrtf(n2) / (1.0f + n2);
      if (pass == 1)  vcur[bb][r] = v1s[bb][r] + v;   // v1+v2 for pass 2
      else            out[((size_t)(blk * BQ) + bb) * (O_ * W_) + r] = v;
    }
    __syncthreads();
  }
}

extern "C" void kernel_launch(void* const* d_in, const int* in_sizes, int n_in,
                              void* d_out, int out_size, void* d_ws, size_t ws_size,
                              hipStream_t stream) {
  const float* x = (const float*)d_in[0];   // [512, 1152, 8]
  const float* W = (const float*)d_in[1];   // [1, 10, 1152, 16, 8]
  float* out = (float*)d_out;               // [512, 10, 16]
  _Float16* Wt = (_Float16*)d_ws;           // 2,949,120 B f16 transposed W

  hipLaunchKernelGGL(wprep, dim3((W4TOT + 255) / 256), dim3(256), 0, stream,
                     (const float4*)W, (uint2*)Wt);
  hipLaunchKernelGGL(digitcaps_fused, dim3(512 / BQ), dim3(NTH), 0, stream,
                     x, Wt, out);
}